// Round 2
// baseline (576.470 us; speedup 1.0000x reference)
//
#include <hip/hip_runtime.h>
#include <cstddef>

// Exact IEEE f32 per-op everywhere (match numpy f32 reference bit-for-bit for
// the top-k ranking path). Explicit fmaf() below is unaffected.
#pragma clang fp contract(off)

// ---------- bf16 helpers (raw ushort representation) ----------
__device__ __forceinline__ float bf2f(unsigned short u) {
    unsigned int v = ((unsigned int)u) << 16;
    return __builtin_bit_cast(float, v);
}
__device__ __forceinline__ unsigned short f2bf(float f) {
    unsigned int x = __builtin_bit_cast(unsigned int, f);
    unsigned int r = (x + 0x7FFFu + ((x >> 16) & 1u)) >> 16;
    return (unsigned short)r;
}

// ---------- dtype-generic load/store ----------
template<bool BF16>
__device__ __forceinline__ float LD(const void* p, size_t i) {
    if constexpr (BF16) return bf2f(((const unsigned short*)p)[i]);
    else return ((const float*)p)[i];
}
template<bool BF16>
__device__ __forceinline__ void ST(void* p, size_t i, float v) {
    if constexpr (BF16) ((unsigned short*)p)[i] = f2bf(v);
    else ((float*)p)[i] = v;
}

// ---------- runtime dtype detection ----------
// g1 = ones(512). f32 storage: word0 = 0x3F800000. bf16 storage: 0x3F803F80.
__global__ void k_detect(const unsigned int* __restrict__ g1u, int* __restrict__ flag) {
    if (threadIdx.x == 0 && blockIdx.x == 0)
        *flag = (g1u[0] == 0x3F803F80u) ? 1 : 0;
}

// ---------- bilinear sample plan, ref-exact f32 arithmetic ----------
struct Samp {
    int o00, o01, o10, o11;      // linear offset y*128+x, -1 if invalid (zero pad)
    float w00, w01, w10, w11;
};
__device__ __forceinline__ float grid_coord(float p) {
    // ref: g = 2p-1; gx = ((g+1)*W - 1)*0.5  (W=H=128), every step rounded f32
    float g = 2.0f * p - 1.0f;
    return ((g + 1.0f) * 128.0f - 1.0f) * 0.5f;
}
__device__ __forceinline__ Samp mk_samp(float px, float py) {
    Samp s;
    float gx = grid_coord(px);
    float gy = grid_coord(py);
    float x0f = floorf(gx), y0f = floorf(gy);
    float wx1 = gx - x0f, wy1 = gy - y0f;
    float wx0 = 1.0f - wx1, wy0 = 1.0f - wy1;
    int x0 = (int)x0f, y0 = (int)y0f;
    int x1 = x0 + 1, y1 = y0 + 1;
    bool vx0 = (x0 >= 0) && (x0 < 128);
    bool vx1 = (x1 >= 0) && (x1 < 128);
    bool vy0 = (y0 >= 0) && (y0 < 128);
    bool vy1 = (y1 >= 0) && (y1 < 128);
    s.o00 = (vx0 && vy0) ? (y0 * 128 + x0) : -1;
    s.o01 = (vx1 && vy0) ? (y0 * 128 + x1) : -1;
    s.o10 = (vx0 && vy1) ? (y1 * 128 + x0) : -1;
    s.o11 = (vx1 && vy1) ? (y1 * 128 + x1) : -1;
    s.w00 = wx0 * wy0; s.w01 = wx1 * wy0;
    s.w10 = wx0 * wy1; s.w11 = wx1 * wy1;
    return s;
}
template<bool BF16>
__device__ __forceinline__ float samp_apply(const void* img, const Samp& s) {
    float v00 = (s.o00 >= 0) ? LD<BF16>(img, s.o00) : 0.f;
    float v01 = (s.o01 >= 0) ? LD<BF16>(img, s.o01) : 0.f;
    float v10 = (s.o10 >= 0) ? LD<BF16>(img, s.o10) : 0.f;
    float v11 = (s.o11 >= 0) ? LD<BF16>(img, s.o11) : 0.f;
    return ((s.w00 * v00 + s.w01 * v01) + s.w10 * v10) + s.w11 * v11;
}

// ---------- kernel 1: sampling points + coarse ----------
// coverage rows are identically zero: c0=trunc(eidx/128/128)=0, c1=trunc((eidx%128)/128)=0
// for all eidx<16384, so the sobel/softmax/top-16 path is dead code.
template<bool BF16>
__global__ __launch_bounds__(384) void k_points(
    const void* __restrict__ out, const void* __restrict__ over_gen,
    const void* __restrict__ rand_point, const int* __restrict__ flag,
    void* __restrict__ d_out, float* __restrict__ pts_ws, float* __restrict__ coarse_ws)
{
    if ((*flag != 0) != BF16) return;
    int b = blockIdx.x;
    int tid = threadIdx.x;
    __shared__ float unc[384];
    __shared__ float pts[128][2];
    size_t outbase = (size_t)b * 2 * 16384;
    float px = LD<BF16>(over_gen, (size_t)(b * 384 + tid) * 2 + 0);
    float py = LD<BF16>(over_gen, (size_t)(b * 384 + tid) * 2 + 1);
    {
        Samp s = mk_samp(px, py);
        float M00 = 0.f, M01 = 0.f, M10 = 0.f, M11 = 0.f;
        float m00 = 0.f, m01 = 0.f, m10 = 0.f, m11 = 0.f;
        if (s.o00 >= 0) { float a = LD<BF16>(out, outbase + s.o00), c = LD<BF16>(out, outbase + 16384 + s.o00); M00 = fmaxf(a, c); m00 = fminf(a, c); }
        if (s.o01 >= 0) { float a = LD<BF16>(out, outbase + s.o01), c = LD<BF16>(out, outbase + 16384 + s.o01); M01 = fmaxf(a, c); m01 = fminf(a, c); }
        if (s.o10 >= 0) { float a = LD<BF16>(out, outbase + s.o10), c = LD<BF16>(out, outbase + 16384 + s.o10); M10 = fmaxf(a, c); m10 = fminf(a, c); }
        if (s.o11 >= 0) { float a = LD<BF16>(out, outbase + s.o11), c = LD<BF16>(out, outbase + 16384 + s.o11); M11 = fmaxf(a, c); m11 = fminf(a, c); }
        float og0 = ((s.w00 * M00 + s.w01 * M01) + s.w10 * M10) + s.w11 * M11;
        float og1 = ((s.w00 * m00 + s.w01 * m01) + s.w10 * m10) + s.w11 * m11;
        unc[tid] = og1 - og0;  // == -(og0 - og1) bitwise
    }
    __syncthreads();
    {   // exact lax.top_k(96): value desc, tie -> lower index; ranks are a permutation
        float v = unc[tid];
        int rank = 0;
        for (int j = 0; j < 384; ++j) {
            float u = unc[j];
            rank += (u > v) || (u == v && j < tid);
        }
        if (rank < 96) { pts[rank][0] = px; pts[rank][1] = py; }
    }
    if (tid < 16) {          // coverage rows: zeros
        pts[96 + tid][0] = 0.f; pts[96 + tid][1] = 0.f;
    } else if (tid < 32) {   // random tail
        int r = tid - 16;
        pts[112 + r][0] = LD<BF16>(rand_point, (size_t)(b * 16 + r) * 2 + 0);
        pts[112 + r][1] = LD<BF16>(rand_point, (size_t)(b * 16 + r) * 2 + 1);
    }
    __syncthreads();
    if (tid < 128) {
        float qx = pts[tid][0], qy = pts[tid][1];
        pts_ws[(b * 128 + tid) * 2 + 0] = qx;
        pts_ws[(b * 128 + tid) * 2 + 1] = qy;
        ST<BF16>(d_out, 2048 + (size_t)(b * 128 + tid) * 2 + 0, qx);  // points output
        ST<BF16>(d_out, 2048 + (size_t)(b * 128 + tid) * 2 + 1, qy);
    }
    if (tid < 256) {  // coarse[b,c,n]
        int c = tid >> 7, n = tid & 127;
        Samp s = mk_samp(pts[n][0], pts[n][1]);
        coarse_ws[(b * 2 + c) * 128 + n] =
            samp_apply<BF16>((const void*)((const char*)out + ((size_t)(b * 2 + c) * 16384) * (BF16 ? 2 : 4)), s);
    }
}

// ---------- kernel 2: fine gather from res2 + feat assembly ----------
template<bool BF16>
__global__ __launch_bounds__(512) void k_fine(
    const void* __restrict__ res2, const float* __restrict__ pts_ws,
    const float* __restrict__ coarse_ws, const int* __restrict__ flag,
    float* __restrict__ feat)
{
    if ((*flag != 0) != BF16) return;
    int blk = blockIdx.x;          // b*128 + n
    int b = blk >> 7, n = blk & 127;
    int ch = threadIdx.x;
    float px = pts_ws[blk * 2 + 0], py = pts_ws[blk * 2 + 1];
    Samp s = mk_samp(px, py);
    const void* img = (const void*)((const char*)res2 + ((size_t)(b * 512 + ch) * 16384) * (BF16 ? 2 : 4));
    feat[(size_t)blk * 514 + 2 + ch] = samp_apply<BF16>(img, s);
    if (ch < 2) feat[(size_t)blk * 514 + ch] = coarse_ws[(b * 2 + ch) * 128 + n];
}

// ---------- kernel 3: feat @ w1 + b1 -> LN -> exact gelu ----------
template<bool BF16>
__global__ __launch_bounds__(256) void k_mlp1(
    const float* __restrict__ feat, const void* __restrict__ w1,
    const void* __restrict__ b1, const void* __restrict__ g1,
    const void* __restrict__ be1, const int* __restrict__ flag,
    float* __restrict__ h1)
{
    if ((*flag != 0) != BF16) return;
    __shared__ float lf[4 * 514];
    __shared__ float red_s[256];
    __shared__ float red_q[256];
    int blk = blockIdx.x;
    int b = blk >> 5, n0 = (blk & 31) * 4;
    int tid = threadIdx.x;
    const float* frow = feat + (size_t)(b * 128 + n0) * 514;
    for (int idx = tid; idx < 4 * 514; idx += 256) lf[idx] = frow[idx];
    __syncthreads();
    float acc[4][2];
#pragma unroll
    for (int r = 0; r < 4; ++r) { acc[r][0] = 0.f; acc[r][1] = 0.f; }
    for (int k = 0; k < 514; ++k) {
        float wa = LD<BF16>(w1, (size_t)k * 512 + tid);
        float wb = LD<BF16>(w1, (size_t)k * 512 + tid + 256);
#pragma unroll
        for (int r = 0; r < 4; ++r) {
            float f = lf[r * 514 + k];
            acc[r][0] = fmaf(f, wa, acc[r][0]);
            acc[r][1] = fmaf(f, wb, acc[r][1]);
        }
    }
    float bb0 = LD<BF16>(b1, tid), bb1 = LD<BF16>(b1, tid + 256);
    float ga = LD<BF16>(g1, tid), gb = LD<BF16>(g1, tid + 256);
    float ea = LD<BF16>(be1, tid), eb = LD<BF16>(be1, tid + 256);
    for (int r = 0; r < 4; ++r) {
        float v0 = acc[r][0] + bb0, v1 = acc[r][1] + bb1;
        red_s[tid] = v0 + v1;
        red_q[tid] = v0 * v0 + v1 * v1;
        __syncthreads();
        for (int s = 128; s > 0; s >>= 1) {
            if (tid < s) { red_s[tid] += red_s[tid + s]; red_q[tid] += red_q[tid + s]; }
            __syncthreads();
        }
        float m = red_s[0] * (1.f / 512.f);
        float var = red_q[0] * (1.f / 512.f) - m * m;
        float rstd = 1.f / sqrtf(var + 1e-5f);
        __syncthreads();
        float h0 = (v0 - m) * rstd * ga + ea;
        float h1v = (v1 - m) * rstd * gb + eb;
        h0  = 0.5f * h0  * (1.f + erff(h0  * 0.70710678118654752f));
        h1v = 0.5f * h1v * (1.f + erff(h1v * 0.70710678118654752f));
        h1[(size_t)(b * 128 + n0 + r) * 512 + tid]       = h0;
        h1[(size_t)(b * 128 + n0 + r) * 512 + tid + 256] = h1v;
    }
}

// ---------- kernel 4: h1 @ w2 + b2 -> LN -> gelu ----------
template<bool BF16>
__global__ __launch_bounds__(256) void k_mlp2(
    const float* __restrict__ h1, const void* __restrict__ w2,
    const void* __restrict__ b2, const void* __restrict__ g2,
    const void* __restrict__ be2, const int* __restrict__ flag,
    float* __restrict__ h2)
{
    if ((*flag != 0) != BF16) return;
    __shared__ float lf[4 * 512];
    __shared__ float red_s[256];
    __shared__ float red_q[256];
    int blk = blockIdx.x;
    int b = blk >> 5, n0 = (blk & 31) * 4;
    int tid = threadIdx.x;
    const float* frow = h1 + (size_t)(b * 128 + n0) * 512;
    for (int idx = tid; idx < 4 * 512; idx += 256) lf[idx] = frow[idx];
    __syncthreads();
    float acc[4] = {0.f, 0.f, 0.f, 0.f};
    for (int k = 0; k < 512; ++k) {
        float w = LD<BF16>(w2, (size_t)k * 256 + tid);
#pragma unroll
        for (int r = 0; r < 4; ++r) acc[r] = fmaf(lf[r * 512 + k], w, acc[r]);
    }
    float bb = LD<BF16>(b2, tid), ga = LD<BF16>(g2, tid), ea = LD<BF16>(be2, tid);
    for (int r = 0; r < 4; ++r) {
        float v = acc[r] + bb;
        red_s[tid] = v;
        red_q[tid] = v * v;
        __syncthreads();
        for (int s = 128; s > 0; s >>= 1) {
            if (tid < s) { red_s[tid] += red_s[tid + s]; red_q[tid] += red_q[tid + s]; }
            __syncthreads();
        }
        float m = red_s[0] * (1.f / 256.f);
        float var = red_q[0] * (1.f / 256.f) - m * m;
        float rstd = 1.f / sqrtf(var + 1e-5f);
        __syncthreads();
        float h = (v - m) * rstd * ga + ea;
        h = 0.5f * h * (1.f + erff(h * 0.70710678118654752f));
        h2[(size_t)(b * 128 + n0 + r) * 256 + tid] = h;
    }
}

// ---------- kernel 5: h2 @ w3 + b3, dropout-mask, + coarse -> rend ----------
template<bool BF16>
__global__ __launch_bounds__(256) void k_out(
    const float* __restrict__ h2, const void* __restrict__ w3,
    const void* __restrict__ b3, const void* __restrict__ mask,
    const float* __restrict__ coarse_ws, const int* __restrict__ flag,
    void* __restrict__ d_out)
{
    if ((*flag != 0) != BF16) return;
    int b = blockIdx.x, tid = threadIdx.x;
    int c = tid & 1, n = tid >> 1;
    const float* row = h2 + (size_t)(b * 128 + n) * 256;
    float acc = 0.f;
    for (int k = 0; k < 256; ++k) acc = fmaf(row[k], LD<BF16>(w3, (size_t)k * 2 + c), acc);
    float pred = acc + LD<BF16>(b3, c);
    int oi = b * 256 + c * 128 + n;
    float rend = pred * LD<BF16>(mask, oi) + coarse_ws[oi];
    ST<BF16>(d_out, oi, rend);
}

template<bool BF16>
static void launch_all(void* const* d_in, void* d_out, const int* flag,
                       float* pts_ws, float* coarse_ws, float* feat, float* h1, float* h2,
                       hipStream_t stream) {
    k_points<BF16><<<8, 384, 0, stream>>>(d_in[2], d_in[3], d_in[4], flag, d_out, pts_ws, coarse_ws);
    k_fine<BF16><<<8 * 128, 512, 0, stream>>>(d_in[1], pts_ws, coarse_ws, flag, feat);
    k_mlp1<BF16><<<8 * 32, 256, 0, stream>>>(feat, d_in[6], d_in[7], d_in[8], d_in[9], flag, h1);
    k_mlp2<BF16><<<8 * 32, 256, 0, stream>>>(h1, d_in[10], d_in[11], d_in[12], d_in[13], flag, h2);
    k_out<BF16><<<8, 256, 0, stream>>>(h2, d_in[14], d_in[15], d_in[5], coarse_ws, flag, d_out);
}

extern "C" void kernel_launch(void* const* d_in, const int* in_sizes, int n_in,
                              void* d_out, int out_size, void* d_ws, size_t ws_size,
                              hipStream_t stream) {
    // setup_inputs order: x(0,unused), res2(1), out(2), over_gen(3), rand_point(4),
    // dropout_mask(5), w1(6), b1(7), g1(8), be1(9), w2(10), b2(11), g2(12),
    // be2(13), w3(14), b3(15).
    int* flag = (int*)d_ws;
    float* fws = (float*)d_ws;
    float* pts_ws    = fws + 16;                 // 8*128*2   = 2048
    float* coarse_ws = pts_ws + 2048;            // 8*2*128   = 2048
    float* feat      = coarse_ws + 2048;         // 8*128*514 = 526336
    float* h1        = feat + 8 * 128 * 514;     // 8*128*512 = 524288
    float* h2        = h1 + 8 * 128 * 512;       // 8*128*256 = 262144

    k_detect<<<1, 1, 0, stream>>>((const unsigned int*)d_in[8], flag);
    launch_all<false>(d_in, d_out, flag, pts_ws, coarse_ws, feat, h1, h2, stream);
    launch_all<true>(d_in, d_out, flag, pts_ws, coarse_ws, feat, h1, h2, stream);
}

// Round 3
// 510.065 us; speedup vs baseline: 1.1302x; 1.1302x over previous
//
#include <hip/hip_runtime.h>
#include <cstddef>

// Exact IEEE f32 per-op (top-k ranking path must match numpy f32 bit-for-bit;
// it did in round 2 -> absmax 0.0). Explicit fmaf() below is unaffected.
#pragma clang fp contract(off)

// ---------- bilinear sample plan, ref-exact f32 arithmetic ----------
struct Samp {
    int o00, o01, o10, o11;      // linear offset y*128+x, -1 if invalid (zero pad)
    float w00, w01, w10, w11;
};
__device__ __forceinline__ float grid_coord(float p) {
    // ref: g = 2p-1; gx = ((g+1)*W - 1)*0.5  (W=H=128), every step rounded f32
    float g = 2.0f * p - 1.0f;
    return ((g + 1.0f) * 128.0f - 1.0f) * 0.5f;
}
__device__ __forceinline__ Samp mk_samp(float px, float py) {
    Samp s;
    float gx = grid_coord(px);
    float gy = grid_coord(py);
    float x0f = floorf(gx), y0f = floorf(gy);
    float wx1 = gx - x0f, wy1 = gy - y0f;
    float wx0 = 1.0f - wx1, wy0 = 1.0f - wy1;
    int x0 = (int)x0f, y0 = (int)y0f;
    int x1 = x0 + 1, y1 = y0 + 1;
    bool vx0 = (x0 >= 0) && (x0 < 128);
    bool vx1 = (x1 >= 0) && (x1 < 128);
    bool vy0 = (y0 >= 0) && (y0 < 128);
    bool vy1 = (y1 >= 0) && (y1 < 128);
    s.o00 = (vx0 && vy0) ? (y0 * 128 + x0) : -1;
    s.o01 = (vx1 && vy0) ? (y0 * 128 + x1) : -1;
    s.o10 = (vx0 && vy1) ? (y1 * 128 + x0) : -1;
    s.o11 = (vx1 && vy1) ? (y1 * 128 + x1) : -1;
    s.w00 = wx0 * wy0; s.w01 = wx1 * wy0;
    s.w10 = wx0 * wy1; s.w11 = wx1 * wy1;
    return s;
}
__device__ __forceinline__ float samp_apply(const float* __restrict__ img, const Samp& s) {
    float v00 = (s.o00 >= 0) ? img[s.o00] : 0.f;
    float v01 = (s.o01 >= 0) ? img[s.o01] : 0.f;
    float v10 = (s.o10 >= 0) ? img[s.o10] : 0.f;
    float v11 = (s.o11 >= 0) ? img[s.o11] : 0.f;
    return ((s.w00 * v00 + s.w01 * v01) + s.w10 * v10) + s.w11 * v11;
}
__device__ __forceinline__ float gelu_exact(float h) {
    return 0.5f * h * (1.f + erff(h * 0.70710678118654752f));
}

// ---------- kernel 1: sampling points + coarse (UNCHANGED math from the pass) ----------
// coverage rows identically zero (trunc collapses edge coords); sobel path dead.
__global__ __launch_bounds__(384) void k_points(
    const float* __restrict__ out, const float* __restrict__ over_gen,
    const float* __restrict__ rand_point,
    float* __restrict__ d_out, float* __restrict__ pts_ws, float* __restrict__ coarse_ws)
{
    int b = blockIdx.x;
    int tid = threadIdx.x;
    __shared__ float unc[384];
    __shared__ float pts[128][2];
    size_t outbase = (size_t)b * 2 * 16384;
    float px = over_gen[(size_t)(b * 384 + tid) * 2 + 0];
    float py = over_gen[(size_t)(b * 384 + tid) * 2 + 1];
    {
        Samp s = mk_samp(px, py);
        float M00 = 0.f, M01 = 0.f, M10 = 0.f, M11 = 0.f;
        float m00 = 0.f, m01 = 0.f, m10 = 0.f, m11 = 0.f;
        if (s.o00 >= 0) { float a = out[outbase + s.o00], c = out[outbase + 16384 + s.o00]; M00 = fmaxf(a, c); m00 = fminf(a, c); }
        if (s.o01 >= 0) { float a = out[outbase + s.o01], c = out[outbase + 16384 + s.o01]; M01 = fmaxf(a, c); m01 = fminf(a, c); }
        if (s.o10 >= 0) { float a = out[outbase + s.o10], c = out[outbase + 16384 + s.o10]; M10 = fmaxf(a, c); m10 = fminf(a, c); }
        if (s.o11 >= 0) { float a = out[outbase + s.o11], c = out[outbase + 16384 + s.o11]; M11 = fmaxf(a, c); m11 = fminf(a, c); }
        float og0 = ((s.w00 * M00 + s.w01 * M01) + s.w10 * M10) + s.w11 * M11;
        float og1 = ((s.w00 * m00 + s.w01 * m01) + s.w10 * m10) + s.w11 * m11;
        unc[tid] = og1 - og0;  // == -(og0 - og1) bitwise
    }
    __syncthreads();
    {   // exact lax.top_k(96): value desc, tie -> lower index; ranks are a permutation
        float v = unc[tid];
        int rank = 0;
        for (int j = 0; j < 384; ++j) {
            float u = unc[j];
            rank += (u > v) || (u == v && j < tid);
        }
        if (rank < 96) { pts[rank][0] = px; pts[rank][1] = py; }
    }
    if (tid < 16) {          // coverage rows: zeros
        pts[96 + tid][0] = 0.f; pts[96 + tid][1] = 0.f;
    } else if (tid < 32) {   // random tail
        int r = tid - 16;
        pts[112 + r][0] = rand_point[(size_t)(b * 16 + r) * 2 + 0];
        pts[112 + r][1] = rand_point[(size_t)(b * 16 + r) * 2 + 1];
    }
    __syncthreads();
    if (tid < 128) {
        float qx = pts[tid][0], qy = pts[tid][1];
        pts_ws[(b * 128 + tid) * 2 + 0] = qx;
        pts_ws[(b * 128 + tid) * 2 + 1] = qy;
        d_out[2048 + (size_t)(b * 128 + tid) * 2 + 0] = qx;  // points output
        d_out[2048 + (size_t)(b * 128 + tid) * 2 + 1] = qy;
    }
    if (tid < 256) {  // coarse[b,c,n]
        int c = tid >> 7, n = tid & 127;
        Samp s = mk_samp(pts[n][0], pts[n][1]);
        coarse_ws[(b * 2 + c) * 128 + n] = samp_apply(out + (size_t)(b * 2 + c) * 16384, s);
    }
}

// ---------- kernel 2: fused gather + MLP + head ----------
// The MLP is row-local (LN over feature axis), so a block owning ROWS=4 (b,n)
// rows runs feat -> h1 -> h2 -> pred entirely in LDS. 256 blocks x 512 thr.
#define ROWS 4
__global__ __launch_bounds__(512) void k_fused(
    const float* __restrict__ res2, const float* __restrict__ pts_ws,
    const float* __restrict__ coarse_ws,
    const float* __restrict__ w1, const float* __restrict__ b1,
    const float* __restrict__ g1, const float* __restrict__ be1,
    const float* __restrict__ w2, const float* __restrict__ b2,
    const float* __restrict__ g2, const float* __restrict__ be2,
    const float* __restrict__ w3, const float* __restrict__ b3,
    const float* __restrict__ mask, float* __restrict__ d_out)
{
    __shared__ float feat[ROWS][514];
    __shared__ float h1s[ROWS][512];
    __shared__ float h2s[ROWS][256];
    __shared__ float part2[256][ROWS];
    __shared__ float pd[8][32];
    __shared__ float red_s[8][ROWS], red_q[8][ROWS];
    __shared__ float stat_m[ROWS], stat_r[ROWS];
    __shared__ float ptsl[ROWS][2];

    int blk = blockIdx.x;
    int b = blk >> 5, n0 = (blk & 31) * ROWS;
    int tid = threadIdx.x;
    int wave = tid >> 6, lane = tid & 63;

    if (tid < ROWS * 2)
        ((float*)ptsl)[tid] = pts_ws[(size_t)(b * 128 + n0) * 2 + tid];
    if (tid >= 64 && tid < 64 + ROWS * 2) {   // coarse -> feat[r][0:2]
        int i = tid - 64, r = i >> 1, c = i & 1;
        feat[r][c] = coarse_ws[(b * 2 + c) * 128 + (n0 + r)];
    }
    __syncthreads();

    // ---- Phase A: fine gather, 4 rows x 512 channels, 16 indep loads/thread ----
#pragma unroll
    for (int r = 0; r < ROWS; ++r) {
        Samp s = mk_samp(ptsl[r][0], ptsl[r][1]);
        const float* img = res2 + ((size_t)(b * 512 + tid) << 14);
        feat[r][2 + tid] = samp_apply(img, s);
    }
    __syncthreads();

    // ---- Phase B: feat @ w1 + b1 -> LN -> gelu -> h1s ----
    int col = tid;  // 0..511
    float acc1[ROWS] = {0.f, 0.f, 0.f, 0.f};
    for (int k = 0; k < 514; ++k) {
        float w = w1[(size_t)k * 512 + col];
#pragma unroll
        for (int r = 0; r < ROWS; ++r) acc1[r] = fmaf(feat[r][k], w, acc1[r]);
    }
    {
        float bb = b1[col], ga = g1[col], ea = be1[col];
        float v[ROWS];
#pragma unroll
        for (int r = 0; r < ROWS; ++r) v[r] = acc1[r] + bb;
#pragma unroll
        for (int r = 0; r < ROWS; ++r) {
            float s = v[r], q = v[r] * v[r];
            for (int off = 32; off > 0; off >>= 1) {
                s += __shfl_down(s, off, 64);
                q += __shfl_down(q, off, 64);
            }
            if (lane == 0) { red_s[wave][r] = s; red_q[wave][r] = q; }
        }
        __syncthreads();
        if (tid < ROWS) {
            float s = 0.f, q = 0.f;
            for (int w8 = 0; w8 < 8; ++w8) { s += red_s[w8][tid]; q += red_q[w8][tid]; }
            float m = s * (1.f / 512.f);
            float var = q * (1.f / 512.f) - m * m;
            stat_m[tid] = m;
            stat_r[tid] = 1.f / sqrtf(var + 1e-5f);
        }
        __syncthreads();
#pragma unroll
        for (int r = 0; r < ROWS; ++r)
            h1s[r][col] = gelu_exact((v[r] - stat_m[r]) * stat_r[r] * ga + ea);
    }
    __syncthreads();

    // ---- Phase C: h1 @ w2 + b2 -> LN -> gelu -> h2s  (split-k x2) ----
    int c2 = tid & 255, kh = tid >> 8;  // kh in {0,1}
    float acc2[ROWS] = {0.f, 0.f, 0.f, 0.f};
    for (int k = 0; k < 256; ++k) {
        int kk = (kh << 8) + k;
        float w = w2[(size_t)kk * 256 + c2];
#pragma unroll
        for (int r = 0; r < ROWS; ++r) acc2[r] = fmaf(h1s[r][kk], w, acc2[r]);
    }
    if (kh == 1) {
#pragma unroll
        for (int r = 0; r < ROWS; ++r) part2[c2][r] = acc2[r];
    }
    __syncthreads();
    float v2[ROWS];
    float ga2 = 0.f, ea2 = 0.f;
    if (kh == 0) {
        float bb2 = b2[c2];
        ga2 = g2[c2]; ea2 = be2[c2];
#pragma unroll
        for (int r = 0; r < ROWS; ++r) {
            v2[r] = (acc2[r] + part2[c2][r]) + bb2;
            float s = v2[r], q = v2[r] * v2[r];
            for (int off = 32; off > 0; off >>= 1) {
                s += __shfl_down(s, off, 64);
                q += __shfl_down(q, off, 64);
            }
            if (lane == 0) { red_s[wave][r] = s; red_q[wave][r] = q; }
        }
    }
    __syncthreads();
    if (tid < ROWS) {
        float s = 0.f, q = 0.f;
        for (int w4 = 0; w4 < 4; ++w4) { s += red_s[w4][tid]; q += red_q[w4][tid]; }
        float m = s * (1.f / 256.f);
        float var = q * (1.f / 256.f) - m * m;
        stat_m[tid] = m;
        stat_r[tid] = 1.f / sqrtf(var + 1e-5f);
    }
    __syncthreads();
    if (kh == 0) {
#pragma unroll
        for (int r = 0; r < ROWS; ++r)
            h2s[r][c2] = gelu_exact((v2[r] - stat_m[r]) * stat_r[r] * ga2 + ea2);
    }
    __syncthreads();

    // ---- Phase D: h2 @ w3 + b3, dropout-mask, + coarse -> rend ----
    if (tid < 256) {
        int rc = tid >> 5, l = tid & 31;   // rc: (r<<1)|c
        int r = rc >> 1, c = rc & 1;
        float p = 0.f;
        for (int k = l; k < 256; k += 32) p = fmaf(h2s[r][k], w3[k * 2 + c], p);
        pd[rc][l] = p;
    }
    __syncthreads();
    if (tid < 8) {
        int r = tid >> 1, c = tid & 1;
        float acc = 0.f;
        for (int l = 0; l < 32; ++l) acc += pd[tid][l];
        float pred = acc + b3[c];
        int oi = b * 256 + c * 128 + (n0 + r);
        d_out[oi] = pred * mask[oi] + coarse_ws[oi];
    }
}

extern "C" void kernel_launch(void* const* d_in, const int* in_sizes, int n_in,
                              void* d_out, int out_size, void* d_ws, size_t ws_size,
                              hipStream_t stream) {
    // setup_inputs order: x(0,unused), res2(1), out(2), over_gen(3), rand_point(4),
    // dropout_mask(5), w1(6), b1(7), g1(8), be1(9), w2(10), b2(11), g2(12),
    // be2(13), w3(14), b3(15). All float32 (verified: absmax 0.0 in round 2).
    const float* res2 = (const float*)d_in[1];
    const float* out  = (const float*)d_in[2];
    const float* over_gen   = (const float*)d_in[3];
    const float* rand_point = (const float*)d_in[4];
    const float* mask = (const float*)d_in[5];
    const float* w1 = (const float*)d_in[6];
    const float* b1 = (const float*)d_in[7];
    const float* g1 = (const float*)d_in[8];
    const float* be1 = (const float*)d_in[9];
    const float* w2 = (const float*)d_in[10];
    const float* b2 = (const float*)d_in[11];
    const float* g2 = (const float*)d_in[12];
    const float* be2 = (const float*)d_in[13];
    const float* w3 = (const float*)d_in[14];
    const float* b3 = (const float*)d_in[15];
    float* o = (float*)d_out;  // rend[0:2048], points[2048:4096]

    float* fws = (float*)d_ws;
    float* pts_ws    = fws;          // 8*128*2 = 2048
    float* coarse_ws = fws + 2048;   // 8*2*128 = 2048

    k_points<<<8, 384, 0, stream>>>(out, over_gen, rand_point, o, pts_ws, coarse_ws);
    k_fused<<<8 * 32, 512, 0, stream>>>(res2, pts_ws, coarse_ws,
                                        w1, b1, g1, be1, w2, b2, g2, be2, w3, b3,
                                        mask, o);
}